// Round 1
// baseline (24836.034 us; speedup 1.0000x reference)
//
#include <hip/hip_runtime.h>
#include <math.h>

// GPT-2-small-ish forward: L=12, B=4, T=1024, D=1024, H=16, HD=64, V=50257
// Round 0: pure-fp32 correctness baseline. All GEMMs on vector ALU (no fp32
// MFMA on CDNA4); bf16-MFMA conversion is the planned round-1+ lever once we
// see the validation tolerance behave.

constexpr int NL  = 12;
constexpr int BB  = 4;
constexpr int TT  = 1024;
constexpr int DD  = 1024;
constexpr int NH  = 16;
constexpr int HD_ = 64;
constexpr int VV  = 50257;
constexpr int FF  = 4096;

typedef float4 f4;

__device__ __forceinline__ float wave_sum(float v) {
#pragma unroll
  for (int o = 32; o > 0; o >>= 1) v += __shfl_down(v, o);
  return v;
}

// ---------------- embedding: x[b,t,:] = wte[idx[b,t],:] + wpe[t,:] ----------
__global__ __launch_bounds__(256) void embed_kernel(const int* __restrict__ idx,
                                                    const float* __restrict__ wte,
                                                    const float* __restrict__ wpe,
                                                    float* __restrict__ x) {
  const int bt = blockIdx.x;           // 0..B*T-1
  const int t  = threadIdx.x;          // 256 threads * float4 = 1024 elems
  const int tok = idx[bt];
  const int pos = bt % TT;
  f4 a = *(const f4*)(wte + (size_t)tok * DD + t * 4);
  f4 p = *(const f4*)(wpe + (size_t)pos * DD + t * 4);
  f4 o; o.x = a.x + p.x; o.y = a.y + p.y; o.z = a.z + p.z; o.w = a.w + p.w;
  *(f4*)(x + (size_t)bt * DD + t * 4) = o;
}

// ---------------- gamma-only layernorm over D=1024 --------------------------
// one block (256 thr) per row; in rows at stride `row_stride`, out rows at DD.
__global__ __launch_bounds__(256) void ln_kernel(const float* __restrict__ in,
                                                 size_t row_stride,
                                                 const float* __restrict__ g,
                                                 float* __restrict__ out) {
  const int t = threadIdx.x;
  const int r = blockIdx.x;
  const float* row = in + (size_t)r * row_stride;
  f4 v = *(const f4*)(row + t * 4);
  __shared__ float red[4];
  float s = v.x + v.y + v.z + v.w;
  s = wave_sum(s);
  if ((t & 63) == 0) red[t >> 6] = s;
  __syncthreads();
  const float mu = (red[0] + red[1] + red[2] + red[3]) * (1.0f / 1024.0f);
  __syncthreads();  // red reuse
  const float dx = v.x - mu, dy = v.y - mu, dz = v.z - mu, dw = v.w - mu;
  float sq = dx * dx + dy * dy + dz * dz + dw * dw;
  sq = wave_sum(sq);
  if ((t & 63) == 0) red[t >> 6] = sq;
  __syncthreads();
  const float var = (red[0] + red[1] + red[2] + red[3]) * (1.0f / 1024.0f);
  const float rs = rsqrtf(var + 1e-5f);
  f4 gv = *(const f4*)(g + t * 4);
  f4 o;
  o.x = dx * rs * gv.x; o.y = dy * rs * gv.y;
  o.z = dz * rs * gv.z; o.w = dw * rs * gv.w;
  *(f4*)(out + (size_t)r * DD + t * 4) = o;
}

// ---------------- fp32 tiled GEMM: C[M,N] = act(A[M,K] @ W[K,N] (+R)) -------
// tile 128x64, BK=16, 256 threads, 8x4 micro-tile.
template <bool RESID, bool GELU>
__global__ __launch_bounds__(256) void gemm_kernel(const float* __restrict__ A,
                                                   const float* __restrict__ W,
                                                   const float* __restrict__ R,
                                                   float* __restrict__ C,
                                                   int M, int N, int K) {
  __shared__ float As[16][136];  // transposed [k][m]; 136*4B = 16B-aligned pitch
  __shared__ float Ws[16][68];   // [k][n]; 68*4B = 16B-aligned pitch
  const int t  = threadIdx.x;
  const int tx = t & 15, ty = t >> 4;
  const int m0 = blockIdx.y * 128, n0 = blockIdx.x * 64;
  const int lam = t >> 2;          // A tile row (and +64)
  const int lak = (t & 3) << 2;    // A tile col (float4)
  const int lwn = (t & 15) << 2;   // W tile col (float4)
  const int lwk = t >> 4;          // W tile row
  float acc[8][4];
#pragma unroll
  for (int i = 0; i < 8; i++)
#pragma unroll
    for (int j = 0; j < 4; j++) acc[i][j] = 0.f;

  const float* Ap0 = A + (size_t)(m0 + lam) * K + lak;
  const float* Ap1 = A + (size_t)(m0 + lam + 64) * K + lak;
  const float* Wp  = W + (size_t)lwk * N + n0 + lwn;

  for (int k0 = 0; k0 < K; k0 += 16) {
    f4 a0 = *(const f4*)(Ap0 + k0);
    f4 a1 = *(const f4*)(Ap1 + k0);
    f4 w0 = *(const f4*)(Wp + (size_t)k0 * N);
    __syncthreads();  // previous iter's LDS reads done
    As[lak + 0][lam] = a0.x; As[lak + 1][lam] = a0.y;
    As[lak + 2][lam] = a0.z; As[lak + 3][lam] = a0.w;
    As[lak + 0][lam + 64] = a1.x; As[lak + 1][lam + 64] = a1.y;
    As[lak + 2][lam + 64] = a1.z; As[lak + 3][lam + 64] = a1.w;
    *(f4*)&Ws[lwk][lwn] = w0;
    __syncthreads();
#pragma unroll
    for (int kk = 0; kk < 16; kk++) {
      f4 av0 = *(const f4*)&As[kk][ty * 4];
      f4 av1 = *(const f4*)&As[kk][ty * 4 + 64];
      f4 wv  = *(const f4*)&Ws[kk][tx * 4];
      const float am[8] = {av0.x, av0.y, av0.z, av0.w, av1.x, av1.y, av1.z, av1.w};
      const float wn[4] = {wv.x, wv.y, wv.z, wv.w};
#pragma unroll
      for (int i = 0; i < 8; i++)
#pragma unroll
        for (int j = 0; j < 4; j++) acc[i][j] = fmaf(am[i], wn[j], acc[i][j]);
    }
  }
#pragma unroll
  for (int i8 = 0; i8 < 8; i8++) {
    const int m = m0 + ty * 4 + (i8 < 4 ? i8 : 64 + (i8 - 4));
    const size_t off = (size_t)m * N + n0 + tx * 4;
    f4 c = {acc[i8][0], acc[i8][1], acc[i8][2], acc[i8][3]};
    if (RESID) {
      f4 r = *(const f4*)(R + off);
      c.x += r.x; c.y += r.y; c.z += r.z; c.w += r.w;
    }
    if (GELU) {
      c.x = 0.5f * c.x * (1.f + erff(c.x * 0.70710678118654752f));
      c.y = 0.5f * c.y * (1.f + erff(c.y * 0.70710678118654752f));
      c.z = 0.5f * c.z * (1.f + erff(c.z * 0.70710678118654752f));
      c.w = 0.5f * c.w * (1.f + erff(c.w * 0.70710678118654752f));
    }
    *(f4*)(C + off) = c;
  }
}

// ---------------- causal flash attention, fp32 ------------------------------
// block = 256 thr handles 16 q-rows of one (b,h); k-tiles of 64 in LDS.
// thread (qrow = t>>4, ln = t&15): 4 scores (k = ln+16*kk), 4 ctx dims
// (d = ln+16*j). Online softmax; 16-lane shfl_xor row reductions.
__global__ __launch_bounds__(256) void attn_kernel(const float* __restrict__ qb,
                                                   const float* __restrict__ kb,
                                                   const float* __restrict__ vb,
                                                   float* __restrict__ ob) {
  const int qt = blockIdx.x;   // 0..T/16-1
  const int bh = blockIdx.y;   // 0..B*H-1
  const int b = bh >> 4, h = bh & 15;
  const int t = threadIdx.x;
  const int qrow = t >> 4, ln = t & 15;
  __shared__ float qs[16][65];  // pitch 65 -> conflict-free scalar access
  __shared__ float ks[64][65];
  __shared__ float vs[64][65];
  __shared__ float ps[16][65];
  {  // stage Q tile (16x64)
    const int r = t >> 4, c = (t & 15) * 4;
    f4 qv = *(const f4*)(qb + ((size_t)(b * TT + qt * 16 + r)) * DD + h * HD_ + c);
    qs[r][c] = qv.x; qs[r][c + 1] = qv.y; qs[r][c + 2] = qv.z; qs[r][c + 3] = qv.w;
  }
  float ctx0 = 0.f, ctx1 = 0.f, ctx2 = 0.f, ctx3 = 0.f;
  float mrun = -1e30f, lrun = 0.f;
  const int qabs = qt * 16 + qrow;
  const int nkt = qt / 4 + 1;  // causal: only tiles with k_min <= q_max
  for (int kt = 0; kt < nkt; kt++) {
    __syncthreads();
#pragma unroll
    for (int it = 0; it < 4; it++) {
      const int r = (t >> 4) + it * 16;
      const int c = (t & 15) * 4;
      const size_t goff = ((size_t)(b * TT + kt * 64 + r)) * DD + h * HD_ + c;
      f4 kv = *(const f4*)(kb + goff);
      f4 vv = *(const f4*)(vb + goff);
      ks[r][c] = kv.x; ks[r][c + 1] = kv.y; ks[r][c + 2] = kv.z; ks[r][c + 3] = kv.w;
      vs[r][c] = vv.x; vs[r][c + 1] = vv.y; vs[r][c + 2] = vv.z; vs[r][c + 3] = vv.w;
    }
    __syncthreads();
    float sc[4] = {0.f, 0.f, 0.f, 0.f};
#pragma unroll 8
    for (int d = 0; d < 64; d++) {
      const float qv = qs[qrow][d];
      sc[0] = fmaf(qv, ks[ln][d], sc[0]);
      sc[1] = fmaf(qv, ks[ln + 16][d], sc[1]);
      sc[2] = fmaf(qv, ks[ln + 32][d], sc[2]);
      sc[3] = fmaf(qv, ks[ln + 48][d], sc[3]);
    }
    float tmax = -1e30f;
#pragma unroll
    for (int kk = 0; kk < 4; kk++) {
      const int kabs = kt * 64 + ln + kk * 16;
      sc[kk] = (kabs <= qabs) ? sc[kk] * 0.125f : -1e30f;
      tmax = fmaxf(tmax, sc[kk]);
    }
#pragma unroll
    for (int o = 8; o > 0; o >>= 1) tmax = fmaxf(tmax, __shfl_xor(tmax, o, 16));
    const float mnew = fmaxf(mrun, tmax);
    const float scale = expf(mrun - mnew);
    float psum = 0.f;
#pragma unroll
    for (int kk = 0; kk < 4; kk++) {
      const float p = expf(sc[kk] - mnew);
      ps[qrow][ln + kk * 16] = p;
      psum += p;
    }
#pragma unroll
    for (int o = 8; o > 0; o >>= 1) psum += __shfl_xor(psum, o, 16);
    lrun = lrun * scale + psum;
    mrun = mnew;
    ctx0 *= scale; ctx1 *= scale; ctx2 *= scale; ctx3 *= scale;
#pragma unroll 8
    for (int k = 0; k < 64; k++) {  // within-wave ps RAW: compiler waitcnt
      const float p = ps[qrow][k];
      ctx0 = fmaf(p, vs[k][ln], ctx0);
      ctx1 = fmaf(p, vs[k][ln + 16], ctx1);
      ctx2 = fmaf(p, vs[k][ln + 32], ctx2);
      ctx3 = fmaf(p, vs[k][ln + 48], ctx3);
    }
  }
  const float inv = 1.0f / lrun;
  const size_t ooff = ((size_t)(b * TT + qabs)) * DD + h * HD_ + ln;
  ob[ooff]      = ctx0 * inv;
  ob[ooff + 16] = ctx1 * inv;
  ob[ooff + 32] = ctx2 * inv;
  ob[ooff + 48] = ctx3 * inv;
}

// ---------------- lm head: out[b,v] = dot(xf[b,:], wte[v,:]) ----------------
__global__ __launch_bounds__(256) void head_kernel(const float* __restrict__ xf,
                                                   const float* __restrict__ wte,
                                                   float* __restrict__ out) {
  const int v = blockIdx.x;
  const int t = threadIdx.x;
  f4 wv = *(const f4*)(wte + (size_t)v * DD + t * 4);
  float p[BB];
#pragma unroll
  for (int b = 0; b < BB; b++) {
    f4 xv = *(const f4*)(xf + b * DD + t * 4);
    p[b] = wv.x * xv.x + wv.y * xv.y + wv.z * xv.z + wv.w * xv.w;
  }
#pragma unroll
  for (int b = 0; b < BB; b++) p[b] = wave_sum(p[b]);
  __shared__ float red[BB][4];
  if ((t & 63) == 0) {
    const int w = t >> 6;
#pragma unroll
    for (int b = 0; b < BB; b++) red[b][w] = p[b];
  }
  __syncthreads();
  if (t < BB) {
    out[(size_t)t * VV + v] = red[t][0] + red[t][1] + red[t][2] + red[t][3];
  }
}

// ---------------- orchestration ---------------------------------------------
extern "C" void kernel_launch(void* const* d_in, const int* in_sizes, int n_in,
                              void* d_out, int out_size, void* d_ws, size_t ws_size,
                              hipStream_t stream) {
  const int*   idx   = (const int*)d_in[0];
  const float* wte   = (const float*)d_in[1];
  const float* wpe   = (const float*)d_in[2];
  const float* ln1_g = (const float*)d_in[3];
  const float* ln2_g = (const float*)d_in[4];
  const float* wq    = (const float*)d_in[5];
  const float* wk    = (const float*)d_in[6];
  const float* wv    = (const float*)d_in[7];
  const float* wo    = (const float*)d_in[8];
  const float* wfc   = (const float*)d_in[9];
  const float* wpr   = (const float*)d_in[10];
  const float* lnf_g = (const float*)d_in[11];
  float* out = (float*)d_out;

  const size_t BTD = (size_t)BB * TT * DD;   // 4 Mi floats
  float* x   = (float*)d_ws;                 // residual stream
  float* h   = x + BTD;                      // LN output / GEMM A
  float* q   = h + BTD;                      // region2 start
  float* k   = q + BTD;
  float* v   = k + BTD;
  float* ctx = v + BTD;
  float* hfc = q;                            // overlay: {q,k,v,ctx} dead when MLP runs
  float* xf  = ctx + BTD;                    // 4 rows, after region2 (hfc ends at ctx+BTD)

  embed_kernel<<<BB * TT, 256, 0, stream>>>(idx, wte, wpe, x);

  const dim3 g1(DD / 64, BB * TT / 128);     // (16, 32) for N=1024 GEMMs
  const dim3 gfc(FF / 64, BB * TT / 128);    // (64, 32) for the FC GEMM
  for (int i = 0; i < NL; i++) {
    const size_t woff  = (size_t)i * DD * DD;
    const size_t wofffc = (size_t)i * DD * FF;
    ln_kernel<<<BB * TT, 256, 0, stream>>>(x, DD, ln1_g + (size_t)i * DD, h);
    gemm_kernel<false, false><<<g1, 256, 0, stream>>>(h, wq + woff, nullptr, q, BB * TT, DD, DD);
    gemm_kernel<false, false><<<g1, 256, 0, stream>>>(h, wk + woff, nullptr, k, BB * TT, DD, DD);
    gemm_kernel<false, false><<<g1, 256, 0, stream>>>(h, wv + woff, nullptr, v, BB * TT, DD, DD);
    attn_kernel<<<dim3(TT / 16, BB * NH), 256, 0, stream>>>(q, k, v, ctx);
    gemm_kernel<true, false><<<g1, 256, 0, stream>>>(ctx, wo + woff, x, x, BB * TT, DD, DD);
    ln_kernel<<<BB * TT, 256, 0, stream>>>(x, DD, ln2_g + (size_t)i * DD, h);
    gemm_kernel<false, true><<<gfc, 256, 0, stream>>>(h, wfc + wofffc, nullptr, hfc, BB * TT, FF, DD);
    gemm_kernel<true, false><<<g1, 256, 0, stream>>>(hfc, wpr + wofffc, x, x, BB * TT, DD, FF);
  }
  // final LN only on the last position (reference slices x[:, -1, :])
  ln_kernel<<<BB, 256, 0, stream>>>(x + (size_t)(TT - 1) * DD, (size_t)TT * DD, lnf_g, xf);
  head_kernel<<<VV, 256, 0, stream>>>(xf, wte, out);
}